// Round 12
// baseline (29.970 us; speedup 1.0000x reference)
//
#include <hip/hip_runtime.h>
#include <math.h>

#define TPB 512
#define WAVES 8
#define RAYS_PB 128      // 4 ray-groups x 32 rays; 2 waves per ray-group
#define PREP_BLK 16
#define PREP_T 128

typedef short short8 __attribute__((ext_vector_type(8)));
typedef float f32x16 __attribute__((ext_vector_type(16)));

__device__ __forceinline__ unsigned int f2bf(float f) {
    unsigned int u = __float_as_uint(f);
    u += 0x7FFFu + ((u >> 16) & 1u);   // round-to-nearest-even
    return u >> 16;
}

// ---------------------------------------------------------------------------
// Prep: pack points as bf16x4 (qx,qy,qz,-0.5|q|^2) uint2; exact-f32 per-block
// maxdist^2 partials. grid = (PREP_BLK, B), block = 128. ~1 point/thread.
// ---------------------------------------------------------------------------
__global__ __launch_bounds__(PREP_T) void prep_kernel(
    const float* __restrict__ c, const float* __restrict__ pc,
    uint2* __restrict__ pts2, float* __restrict__ gpart, int N)
{
    int b = blockIdx.y, blk = blockIdx.x;
    const float* cb = c + b * 25;
    float ox = cb[3], oy = cb[7], oz = cb[11];
    const float* p = pc + (size_t)b * N * 3;
    int per = (N + PREP_BLK - 1) / PREP_BLK;
    int n0 = blk * per;
    int n1 = min(n0 + per, N);
    float mx = 0.0f;
    for (int n = n0 + threadIdx.x; n < n1; n += PREP_T) {
        float qx = p[n * 3], qy = p[n * 3 + 1], qz = p[n * 3 + 2];
        float qn = qx * qx + qy * qy + qz * qz;
        pts2[(size_t)b * N + n] = make_uint2(
            f2bf(qx) | (f2bf(qy) << 16),
            f2bf(qz) | (f2bf(-0.5f * qn) << 16));
        float dx = qx - ox, dy = qy - oy, dz = qz - oz;
        mx = fmaxf(mx, dx * dx + dy * dy + dz * dz);
    }
    for (int off = 32; off; off >>= 1) mx = fmaxf(mx, __shfl_down(mx, off));
    __shared__ float sm[PREP_T / 64];
    if ((threadIdx.x & 63) == 0) sm[threadIdx.x >> 6] = mx;
    __syncthreads();
    if (threadIdx.x == 0) {
        float m2 = sm[0];
        for (int i = 1; i < PREP_T / 64; ++i) m2 = fmaxf(m2, sm[i]);
        gpart[b * PREP_BLK + blk] = m2;
    }
}

// ---------------------------------------------------------------------------
// MFMA main: grid = (ceil(M/128), B), block = 512 (8 waves), 2 blocks/CU.
// Wave w = 2*rg + half: handles ray-group rg (32 rays) x point-half `half`.
// NO LDS staging, NO in-loop barriers: the B-fragment is per-lane data, so
// lane c loads packed point (t*32+c) straight from global (L1-resident,
// coalesced dwordx2). Per tile: 1 load + 1 MFMA + 16 v_max.
//   S[r,c] = p4[r].q4[c] via mfma_f32_32x32x16_bf16 (A k=4..15 zero)
//   min_n d2 = pn - 2*max_n S  (pn, maxdist, mask exact f32)
// C/D layout (HW-verified R11): col=lane&31, row=(r&3)+8*(r>>2)+4*(lane>>5).
// Deterministic: fixed-order reductions, no atomics.
// ---------------------------------------------------------------------------
__global__ __launch_bounds__(TPB) void chamfer_main(
    const float* __restrict__ c, const float* __restrict__ depth,
    const uint2* __restrict__ pts2, const float* __restrict__ gpart,
    float2* __restrict__ partial, int res, int M, int N)
{
    __shared__ float redR[WAVES][32][33];     // 33.8 KB
    __shared__ float pnL[RAYS_PB], depL[RAYS_PB];
    __shared__ float bs[2], bc[2];

    int tile = blockIdx.x, b = blockIdx.y;
    int tid = threadIdx.x, w = tid >> 6, lane = tid & 63;
    int colb = lane & 31, hh = lane >> 5;
    int rg = w >> 1, half = w & 1;

    const float* cb = c + b * 25;
    float fx = cb[16], sk = cb[17], cx = cb[18];
    float fy = cb[20], cy = cb[21];
    float ox = cb[3], oy = cb[7], oz = cb[11];

    // maxdist threshold (uniform scalar loads)
    float m2 = 0.0f;
    #pragma unroll
    for (int i = 0; i < PREP_BLK; ++i) m2 = fmaxf(m2, gpart[b * PREP_BLK + i]);
    float thr = sqrtf(m2);

    // ---- ray setup: ray m = tile*128 + rg*32 + colb ----
    short8 afrag = {0, 0, 0, 0, 0, 0, 0, 0};
    {
        int m = tile * RAYS_PB + rg * 32 + colb;
        int mm = min(m, M - 1);
        int i = mm / res, j = mm - i * res;
        float x = (j + 0.5f) / (float)res;
        float y = (i + 0.5f) / (float)res;
        float xl = (x - cx + cy * sk / fy - sk * y / fy) / fx;
        float yl = (y - cy) / fy;
        float wx = cb[0] * xl + cb[1] * yl + cb[2] + cb[3];
        float wy = cb[4] * xl + cb[5] * yl + cb[6] + cb[7];
        float wz = cb[8] * xl + cb[9] * yl + cb[10] + cb[11];
        float dx = wx - ox, dy = wy - oy, dz = wz - oz;
        float nrm = fmaxf(sqrtf(dx * dx + dy * dy + dz * dz), 1e-12f);
        dx /= nrm; dy /= nrm; dz /= nrm;
        float d = depth[(size_t)b * M + mm];
        float px_ = fmaf(d, dx, ox);
        float py_ = fmaf(d, dy, oy);
        float pz_ = fmaf(d, dz, oz);
        float pn_ = px_ * px_ + py_ * py_ + pz_ * pz_;
        if (hh == 0) {
            afrag[0] = (short)f2bf(px_);
            afrag[1] = (short)f2bf(py_);
            afrag[2] = (short)f2bf(pz_);
            afrag[3] = (short)0x3F80;   // 1.0 bf16
            if (half == 0) {
                pnL[rg * 32 + colb] = pn_;
                depL[rg * 32 + colb] = d;
            }
        }
    }

    // ---- point sweep: this wave's half of the point tiles ----
    const f32x16 zacc = {0.f,0.f,0.f,0.f,0.f,0.f,0.f,0.f,
                         0.f,0.f,0.f,0.f,0.f,0.f,0.f,0.f};
    float mx[16];
    #pragma unroll
    for (int r = 0; r < 16; ++r) mx[r] = -3.4e38f;

    int ntt = (N + 31) >> 5;
    int nh = (ntt + 1) >> 1;
    int t0 = half * nh;
    int t1 = min(ntt, t0 + nh);
    const uint2* pq = pts2 + (size_t)b * N;

    #pragma unroll 8
    for (int t = t0; t < t1; ++t) {
        int idx = min(t * 32 + colb, N - 1);   // clamped dups: harmless for max
        uint2 qv = pq[idx];                    // coalesced dwordx2, L1-hit
        union { uint4 u; short8 s; } bu;
        bu.u = make_uint4(qv.x, qv.y, 0u, 0u);
        f32x16 dacc = __builtin_amdgcn_mfma_f32_32x32x16_bf16(
            afrag, bu.s, zacc, 0, 0, 0);
        #pragma unroll
        for (int r = 0; r < 16; ++r) mx[r] = fmaxf(mx[r], dacc[r]);
    }

    // ---- dump per-(row,col) maxes ----
    #pragma unroll
    for (int r = 0; r < 16; ++r) {
        int row = (r & 3) + 8 * (r >> 2) + 4 * hh;
        redR[w][row][colb] = mx[r];
    }
    __syncthreads();

    // ---- epilogue: thread tid (<128) owns ray tid; combine halves+cols ----
    float s = 0.f, cnt = 0.f;
    if (tid < RAYS_PB) {
        int rg2 = tid >> 5, row = tid & 31;
        float mxx = -3.4e38f;
        #pragma unroll
        for (int col = 0; col < 32; ++col)
            mxx = fmaxf(mxx, fmaxf(redR[2 * rg2][row][col],
                                   redR[2 * rg2 + 1][row][col]));
        int mray = tile * RAYS_PB + tid;
        if (mray < M) {
            float md = fmaxf(fmaf(-2.0f, mxx, pnL[tid]), 0.0f);
            if (depL[tid] < thr) { s = md; cnt = 1.0f; }
        }
    }
    for (int off = 32; off; off >>= 1) {
        s += __shfl_down(s, off);
        cnt += __shfl_down(cnt, off);
    }
    if (tid < RAYS_PB && lane == 0) { bs[w] = s; bc[w] = cnt; }
    __syncthreads();
    if (tid == 0) {
        float S = bs[0] + bs[1], C = bc[0] + bc[1];
        partial[(size_t)b * gridDim.x + blockIdx.x] = make_float2(S, C);
    }
}

// ---------------------------------------------------------------------------
// Finalize: ONE block; wave w reduces batch w's ntiles partials.
// ---------------------------------------------------------------------------
__global__ __launch_bounds__(1024) void finalize_kernel(
    const float2* __restrict__ partial, float* __restrict__ out,
    int ntiles, int B)
{
    int w = threadIdx.x >> 6, lane = threadIdx.x & 63;
    if (w >= B) return;
    float S = 0.f, C = 0.f;
    for (int i = lane; i < ntiles; i += 64) {
        float2 p = partial[(size_t)w * ntiles + i];
        S += p.x; C += p.y;
    }
    for (int off = 32; off; off >>= 1) {
        S += __shfl_down(S, off);
        C += __shfl_down(C, off);
    }
    if (lane == 0) out[w] = S / fmaxf(C, 1.0f);
}

extern "C" void kernel_launch(void* const* d_in, const int* in_sizes, int n_in,
                              void* d_out, int out_size, void* d_ws, size_t ws_size,
                              hipStream_t stream) {
    const float* c     = (const float*)d_in[0];
    const float* depth = (const float*)d_in[1];
    const float* pc    = (const float*)d_in[2];

    int B = in_sizes[0] / 25;
    int M = in_sizes[1] / B;
    int N = in_sizes[2] / (3 * B);
    int res = 1;
    while (res * res < M) ++res;

    char* base = (char*)d_ws;
    uint2* pts2 = (uint2*)base;
    size_t o = (size_t)B * N * sizeof(uint2);
    o = (o + 255) & ~(size_t)255;
    float* gpart = (float*)(base + o);
    o += (size_t)B * PREP_BLK * sizeof(float);
    o = (o + 255) & ~(size_t)255;
    float2* partial = (float2*)(base + o);

    int ntiles = (M + RAYS_PB - 1) / RAYS_PB;

    prep_kernel<<<dim3(PREP_BLK, B), PREP_T, 0, stream>>>(c, pc, pts2, gpart, N);
    chamfer_main<<<dim3(ntiles, B), TPB, 0, stream>>>(c, depth, pts2, gpart,
                                                      partial, res, M, N);
    finalize_kernel<<<1, B * 64, 0, stream>>>(partial, (float*)d_out,
                                              ntiles, B);
}